// Round 1
// baseline (368.438 us; speedup 1.0000x reference)
//
#include <hip/hip_runtime.h>
#include <hip/hip_bf16.h>
#include <math.h>

#define B 64
#define N 512
#define C 1024
#define K_NEIGH 32
// band half-width: must satisfy DELTA - bisect_window/2 - E > E, where
// E ~ 0.15 (9-sigma bound on fp16-hi GEMM error) and window = 2800/2^14 = 0.17.
// 0.625 - 0.085 - 0.15 = 0.39 > 0.15  -> non-band elements strictly separated
// from the true 32nd-rank cut; band candidates are exactly rechecked in fp32.
#define DELTA 0.625f
#define BISECT_ITERS 14

typedef __attribute__((ext_vector_type(8))) _Float16 half8;
typedef __attribute__((ext_vector_type(4))) float f32x4;

__device__ __forceinline__ half8 cvt8(float4 a, float4 b) {
    half8 g;
    g[0] = (_Float16)a.x; g[1] = (_Float16)a.y; g[2] = (_Float16)a.z; g[3] = (_Float16)a.w;
    g[4] = (_Float16)b.x; g[5] = (_Float16)b.y; g[6] = (_Float16)b.z; g[7] = (_Float16)b.w;
    return g;
}

// ---------------------------------------------------------------------------
// Kernel 1: S[b] = fp16(x[b]) * fp16(x[b])^T via f16 MFMA (hi-only).
// Full 4x4 grid of 128x128 tiles per batch (no triangle trick): 1024 blocks
// = exactly 4 blocks/CU co-resident, every store coalesced to the block's own
// tile (the old symmetric write was a 4B/lane scatter at 2KB stride).
// BK=64: LDS = 2 x 16KB, one barrier pair per 64 K (was per 32).
// Diagonal tiles (ti==tj) skip B staging and read fragments from Ah.
// LDS granule layout: granule (s,row) = 8 fp16 of k=s*8.. at index s*128+row
//   -> frag read lane l: 16 consecutive granules per quad, conflict-free.
// A-frag: A[m=lane&15][k=quad*8+j]; C/D: col=lane&15, row=quad*4+reg.
// ---------------------------------------------------------------------------
__global__ __launch_bounds__(256, 4) void gemm_f16(const float* __restrict__ x,
                                                   float* __restrict__ S) {
    __shared__ half8 Ah[1024], Bh[1024];   // 2 x 16KB

    // XCD-aware swizzle: XCD = id%8 receives 8 whole batches (16 tiles each),
    // so each XCD's L2 streams ~2 complete 2MB batches at a time instead of
    // strips of all 64 batches.
    const int id   = blockIdx.x;           // 0..1023
    const int xcd  = id & 7;
    const int slot = id >> 3;              // 0..127
    const int b    = xcd + 8 * (slot >> 4);
    const int tile = slot & 15;
    const int ti = tile >> 2, tj = tile & 3;
    const int row0A = ti * 128;
    const int row0B = tj * 128;
    const float* xb = x + (size_t)b * N * C;
    const bool diag = (ti == tj);

    const int t    = threadIdx.x;
    const int w    = t >> 6;
    const int lane = t & 63;
    const int quad = lane >> 4;
    const int lid  = lane & 15;
    const int wr   = (w >> 1) * 64;
    const int wc   = (w & 1) * 64;

    // staging: thread t -> row (t>>1), k-half (t&1)*32 (granules sgb..sgb+3)
    const int srow = t >> 1;
    const int sgb  = (t & 1) * 4;
    const int koff = (t & 1) * 32;

    f32x4 acc[4][4];
#pragma unroll
    for (int r = 0; r < 4; r++)
#pragma unroll
        for (int c = 0; c < 4; c++)
#pragma unroll
            for (int e = 0; e < 4; e++) acc[r][c][e] = 0.f;

    for (int kt = 0; kt < C; kt += 64) {
        {
            const float4* pa = (const float4*)(xb + (size_t)(row0A + srow) * C + kt + koff);
            float4 f0 = pa[0], f1 = pa[1], f2 = pa[2], f3 = pa[3];
            float4 f4 = pa[4], f5 = pa[5], f6 = pa[6], f7 = pa[7];
            Ah[(sgb + 0) * 128 + srow] = cvt8(f0, f1);
            Ah[(sgb + 1) * 128 + srow] = cvt8(f2, f3);
            Ah[(sgb + 2) * 128 + srow] = cvt8(f4, f5);
            Ah[(sgb + 3) * 128 + srow] = cvt8(f6, f7);
        }
        if (!diag) {
            const float4* pb = (const float4*)(xb + (size_t)(row0B + srow) * C + kt + koff);
            float4 f0 = pb[0], f1 = pb[1], f2 = pb[2], f3 = pb[3];
            float4 f4 = pb[4], f5 = pb[5], f6 = pb[6], f7 = pb[7];
            Bh[(sgb + 0) * 128 + srow] = cvt8(f0, f1);
            Bh[(sgb + 1) * 128 + srow] = cvt8(f2, f3);
            Bh[(sgb + 2) * 128 + srow] = cvt8(f4, f5);
            Bh[(sgb + 3) * 128 + srow] = cvt8(f6, f7);
        }
        __syncthreads();

        const half8* Bs = diag ? Ah : Bh;
#pragma unroll
        for (int ks = 0; ks < 2; ks++) {
            const int so = (ks * 4 + quad) * 128;
            half8 vb[4];
#pragma unroll
            for (int c = 0; c < 4; c++) vb[c] = Bs[so + wc + c * 16 + lid];
#pragma unroll
            for (int r = 0; r < 4; r++) {
                half8 va = Ah[so + wr + r * 16 + lid];
#pragma unroll
                for (int c = 0; c < 4; c++)
                    acc[r][c] = __builtin_amdgcn_mfma_f32_16x16x32_f16(va, vb[c], acc[r][c], 0, 0, 0);
            }
        }
        __syncthreads();
    }

    float* Sb = S + (size_t)b * N * N;
#pragma unroll
    for (int r = 0; r < 4; r++) {
#pragma unroll
        for (int c = 0; c < 4; c++) {
#pragma unroll
            for (int e = 0; e < 4; e++) {
                const int grow = row0A + wr + r * 16 + quad * 4 + e;
                const int gcol = row0B + wc + c * 16 + lid;
                Sb[(size_t)grow * N + gcol] = acc[r][c][e];
            }
        }
    }
}

// ---------------------------------------------------------------------------
// Kernel 2: per row -- ballot-popcount bisection for a pivot P with
// #{S' > P+d} <= 31 and #{S' >= P-d} >= 32; band [P-d, P+d] rechecked with
// wave-cooperative exact fp32 dots; exact threshold among band; emit
// 512-bit adjacency mask + deg^-0.5. One wave per row, 4 rows/block.
// ---------------------------------------------------------------------------
__global__ __launch_bounds__(256) void thresh_mask(const float* __restrict__ S,
                                                   const float* __restrict__ x,
                                                   unsigned long long* __restrict__ masks,
                                                   float* __restrict__ dinv) {
    const int row  = blockIdx.x * 4 + (threadIdx.x >> 6);
    const int lane = threadIdx.x & 63;
    const float* Srow = S + (size_t)row * N;

    float v0[8];
#pragma unroll
    for (int k = 0; k < 8; k++) v0[k] = Srow[lane + 64 * k];   // col = lane + 64k

    // --- bisection: invariant cnt(lo) >= 32, cnt(hi) <= 31, cnt(p)=#{v>p} ---
    float lo = -1400.f, hi = 1400.f;   // |S'| <= ~1300 (diag chi2 max) + margin
    for (int it = 0; it < BISECT_ITERS; it++) {
        const float mid = 0.5f * (lo + hi);
        int c = 0;
#pragma unroll
        for (int k = 0; k < 8; k++) c += __popcll(__ballot(v0[k] > mid));
        if (c >= K_NEIGH) lo = mid; else hi = mid;
    }
    const float P   = 0.5f * (lo + hi);
    const float hiB = P + DELTA, loB = P - DELTA;

    // certainly-in count (<= 31 by construction)
    int cA = 0;
#pragma unroll
    for (int k = 0; k < 8; k++) cA += __popcll(__ballot(v0[k] > hiB));
    const int m_need = K_NEIGH - cA;   // >= 1

    // band candidates: one per lane
    int cnt = 0, myj = -1;
#pragma unroll
    for (int kq = 0; kq < 8; kq++) {
        unsigned long long bm = __ballot(v0[kq] >= loB && v0[kq] <= hiB);
        while (bm) {
            int bl = __ffsll(bm) - 1;
            bm &= bm - 1;
            if (cnt == lane) myj = bl + 64 * kq;
            cnt++;
        }
    }
    const int nc = cnt < 64 ? cnt : 64;

    // wave-cooperative exact dots: lane holds xi[q*256 + lane*4 .. +3]
    const int bb_ = row >> 9, ii = row & (N - 1);
    const float* xi = x + ((size_t)bb_ * N + ii) * C;
    float4 ai[4];
#pragma unroll
    for (int q = 0; q < 4; q++) ai[q] = *(const float4*)(xi + q * 256 + lane * 4);

    float ex = -INFINITY;
    for (int c2 = 0; c2 < nc; c2++) {
        const int j = __shfl(myj, c2);
        const float* xj = x + ((size_t)bb_ * N + j) * C;
        float s = 0.f;
#pragma unroll
        for (int q = 0; q < 4; q++) {
            float4 bv = *(const float4*)(xj + q * 256 + lane * 4);
            s = fmaf(ai[q].x, bv.x, s);
            s = fmaf(ai[q].y, bv.y, s);
            s = fmaf(ai[q].z, bv.z, s);
            s = fmaf(ai[q].w, bv.w, s);
        }
#pragma unroll
        for (int off = 32; off > 0; off >>= 1) s += __shfl_xor(s, off);
        if (lane == c2) ex = s;   // deterministic per (i,j)
    }

    // exact threshold T = m_need-th largest band value (tie-correct)
    float val = ex, T = -INFINITY;
    for (int it = 0; it < m_need; it++) {
        float M = val;
#pragma unroll
        for (int off = 32; off > 0; off >>= 1) M = fmaxf(M, __shfl_xor(M, off));
        T = M;
        unsigned long long ball = __ballot(val == M);
        int first = __ffsll(ball) - 1;
        if (lane == first) val = -INFINITY;
    }
    const int dec = (lane < nc && ex >= T) ? 1 : 0;

    // adjacency bits: certain-above -> 1, band -> exact decision, else 0
    int bits[8];
#pragma unroll
    for (int kq = 0; kq < 8; kq++) bits[kq] = (v0[kq] > hiB) ? 1 : 0;
    for (int c2 = 0; c2 < nc; c2++) {
        int j = __shfl(myj, c2);
        int d = __shfl(dec, c2);
        if ((j & 63) == lane) bits[j >> 6] = d;
    }

    unsigned long long msk[8];
    int deg = 0;
#pragma unroll
    for (int kq = 0; kq < 8; kq++) {
        msk[kq] = __ballot(bits[kq] != 0);
        deg += __popcll(msk[kq]);
    }
    if (lane == 0) {
#pragma unroll
        for (int kq = 0; kq < 8; kq++) masks[(size_t)row * 8 + kq] = msk[kq];
        dinv[row] = rsqrtf((float)deg);
    }
}

// ---------------------------------------------------------------------------
// Kernel 3: out[b,i,j] = maskbit ? dinv[b,i]*dinv[b,j] : 0  (writes over S')
// ---------------------------------------------------------------------------
__global__ __launch_bounds__(256) void scale_adj(float* __restrict__ Sout,
                                                 const unsigned long long* __restrict__ masks,
                                                 const float* __restrict__ dinv) {
    const int idx = blockIdx.x * 256 + threadIdx.x;   // float4 index
    const int jq = idx & 127;
    const int i  = (idx >> 7) & (N - 1);
    const int b  = idx >> 16;
    const int row = (b << 9) | i;
    const int j0 = jq * 4;

    const unsigned long long mk = masks[(size_t)row * 8 + (j0 >> 6)];
    const float di = dinv[row];
    float4 dj = ((const float4*)dinv)[(b << 7) | jq];

    float4 o;
    o.x = ((mk >> ((j0 + 0) & 63)) & 1ull) ? di * dj.x : 0.f;
    o.y = ((mk >> ((j0 + 1) & 63)) & 1ull) ? di * dj.y : 0.f;
    o.z = ((mk >> ((j0 + 2) & 63)) & 1ull) ? di * dj.z : 0.f;
    o.w = ((mk >> ((j0 + 3) & 63)) & 1ull) ? di * dj.w : 0.f;
    ((float4*)Sout)[idx] = o;
}

// ---------------------------------------------------------------------------
extern "C" void kernel_launch(void* const* d_in, const int* in_sizes, int n_in,
                              void* d_out, int out_size, void* d_ws, size_t ws_size,
                              hipStream_t stream) {
    const float* x = (const float*)d_in[0];
    float* out = (float*)d_out;                      // stages S', then final out
    unsigned long long* masks = (unsigned long long*)d_ws;     // B*N*8 u64 = 2MB
    float* dinv = (float*)(masks + (size_t)B * N * 8);         // B*N floats

    gemm_f16<<<dim3(B * 16), 256, 0, stream>>>(x, out);        // 1024 blocks = 4/CU
    thresh_mask<<<B * N / 4, 256, 0, stream>>>(out, x, masks, dinv);
    const int total4 = B * N * N / 4;
    scale_adj<<<total4 / 256, 256, 0, stream>>>(out, masks, dinv);
}

// Round 2
// 308.148 us; speedup vs baseline: 1.1957x; 1.1957x over previous
//
#include <hip/hip_runtime.h>
#include <hip/hip_bf16.h>
#include <math.h>

#define B 64
#define N 512
#define C 1024
#define K_NEIGH 32
// band half-width: must satisfy DELTA - bisect_window/2 - E > E, where
// E ~ 0.15 (9-sigma bound on fp16-hi GEMM error) and window = 2800/2^14 = 0.17.
// 0.625 - 0.085 - 0.15 = 0.39 > 0.15  -> non-band elements strictly separated
// from the true 32nd-rank cut; band candidates are exactly rechecked in fp32.
#define DELTA 0.625f
#define BISECT_ITERS 14

typedef __attribute__((ext_vector_type(8))) _Float16 half8;
typedef __attribute__((ext_vector_type(4))) float f32x4;

__device__ __forceinline__ half8 cvt8(float4 a, float4 b) {
    half8 g;
    g[0] = (_Float16)a.x; g[1] = (_Float16)a.y; g[2] = (_Float16)a.z; g[3] = (_Float16)a.w;
    g[4] = (_Float16)b.x; g[5] = (_Float16)b.y; g[6] = (_Float16)b.z; g[7] = (_Float16)b.w;
    return g;
}

// ---------------------------------------------------------------------------
// Kernel 1: S[b] = fp16(x[b]) * fp16(x[b])^T via f16 MFMA (hi-only).
// 256x256 tile, 512 thr = 8 waves (2x4 of 128x64), BK=32, 2-phase pipeline:
//   issue global loads for K-step t+1 (regs) -> ds_read+MFMA on buf[cur]
//   -> cvt+ds_write into buf[cur^1] -> ONE barrier -> flip.
// Prefetch targets the other LDS buffer, so one barrier/iter suffices
// (write(t,buf^1) < bar < read(t+1,buf^1); read(t,cur) < bar < write(t+1,cur)).
// Full 2x2 tile grid per batch: 256 blocks = exactly 1/CU, stores coalesced,
// no transpose scatter. Diagonal tiles skip B staging (read frags from Ah).
// LDS granule layout (proven in prior rounds): granule (s,row) = 8 fp16 of
// k=s*8.. at index s*256+row; frag read = 16 consecutive granules = 256B.
// A-frag: A[m=lane&15][k=quad*8+j]; C/D: col=lane&15, row=quad*4+reg.
// ---------------------------------------------------------------------------
__global__ __launch_bounds__(512, 2) void gemm_f16(const float* __restrict__ x,
                                                   float* __restrict__ S) {
    __shared__ half8 Ah[2][1024];   // 2 x 16KB  (4 granule-cols x 256 rows)
    __shared__ half8 Bh[2][1024];   // 2 x 16KB

    // XCD-aware swizzle: XCD = id%8 owns batches xcd*8..+7; the 4 tiles of a
    // batch are consecutive slots -> co-resident on one XCD, share x[b] in L2.
    const int id   = blockIdx.x;           // 0..255
    const int xcd  = id & 7;
    const int slot = id >> 3;              // 0..31
    const int b    = xcd * 8 + (slot >> 2);
    const int tile = slot & 3;
    const int ti = tile >> 1, tj = tile & 1;
    const int row0 = ti * 256;
    const int col0 = tj * 256;
    const float* xb = x + (size_t)b * N * C;
    const bool diag = (ti == tj);

    const int t    = threadIdx.x;
    const int w    = t >> 6;
    const int lane = t & 63;
    const int quad = lane >> 4;
    const int lid  = lane & 15;
    const int wr   = (w >> 2) * 128;       // 2 wave-rows of 128
    const int wc   = (w & 3) * 64;         // 4 wave-cols of 64

    // staging: thread t -> row (t>>1), k-half (t&1)*16 floats (granules s0,s0+1)
    const int srow = t >> 1;
    const int s0   = (t & 1) * 2;
    const int koff = (t & 1) * 16;

    f32x4 acc[8][4];
#pragma unroll
    for (int r = 0; r < 8; r++)
#pragma unroll
        for (int c = 0; c < 4; c++)
#pragma unroll
            for (int e = 0; e < 4; e++) acc[r][c][e] = 0.f;

    const float* pArow = xb + (size_t)(row0 + srow) * C + koff;
    const float* pBrow = xb + (size_t)(col0 + srow) * C + koff;

    float4 ra[4], rb[4];
    // ---- prologue: stage K-step 0 ----
    {
        const float4* pa = (const float4*)pArow;
#pragma unroll
        for (int i = 0; i < 4; i++) ra[i] = pa[i];
        if (!diag) {
            const float4* pb = (const float4*)pBrow;
#pragma unroll
            for (int i = 0; i < 4; i++) rb[i] = pb[i];
        }
        Ah[0][s0 * 256 + srow]       = cvt8(ra[0], ra[1]);
        Ah[0][(s0 + 1) * 256 + srow] = cvt8(ra[2], ra[3]);
        if (!diag) {
            Bh[0][s0 * 256 + srow]       = cvt8(rb[0], rb[1]);
            Bh[0][(s0 + 1) * 256 + srow] = cvt8(rb[2], rb[3]);
        }
    }
    __syncthreads();

    int cur = 0;
    const int NIT = C / 32;                 // 32 K-steps
    for (int it = 0; it < NIT; ++it) {
        const bool more = (it + 1) < NIT;
        // ---- issue next-tile loads early (latency hides under MFMA) ----
        if (more) {
            const float4* pa = (const float4*)(pArow + (it + 1) * 32);
#pragma unroll
            for (int i = 0; i < 4; i++) ra[i] = pa[i];
            if (!diag) {
                const float4* pb = (const float4*)(pBrow + (it + 1) * 32);
#pragma unroll
                for (int i = 0; i < 4; i++) rb[i] = pb[i];
            }
        }
        // ---- compute current buffer ----
        const half8* Ab = &Ah[cur][0];
        const half8* Bb = diag ? Ab : &Bh[cur][0];
        half8 vb[4];
#pragma unroll
        for (int c = 0; c < 4; c++) vb[c] = Bb[quad * 256 + wc + c * 16 + lid];
        __builtin_amdgcn_s_setprio(1);
#pragma unroll
        for (int r = 0; r < 8; r++) {
            half8 va = Ab[quad * 256 + wr + r * 16 + lid];
#pragma unroll
            for (int c = 0; c < 4; c++)
                acc[r][c] = __builtin_amdgcn_mfma_f32_16x16x32_f16(va, vb[c], acc[r][c], 0, 0, 0);
        }
        __builtin_amdgcn_s_setprio(0);
        // ---- convert + write next tile into the other buffer ----
        if (more) {
            const int nb = cur ^ 1;
            Ah[nb][s0 * 256 + srow]       = cvt8(ra[0], ra[1]);
            Ah[nb][(s0 + 1) * 256 + srow] = cvt8(ra[2], ra[3]);
            if (!diag) {
                Bh[nb][s0 * 256 + srow]       = cvt8(rb[0], rb[1]);
                Bh[nb][(s0 + 1) * 256 + srow] = cvt8(rb[2], rb[3]);
            }
        }
        __syncthreads();
        cur ^= 1;
    }

    float* Sb = S + (size_t)b * N * N;
#pragma unroll
    for (int r = 0; r < 8; r++) {
#pragma unroll
        for (int c = 0; c < 4; c++) {
#pragma unroll
            for (int e = 0; e < 4; e++) {
                const int grow = row0 + wr + r * 16 + quad * 4 + e;
                const int gcol = col0 + wc + c * 16 + lid;
                Sb[(size_t)grow * N + gcol] = acc[r][c][e];
            }
        }
    }
}

// ---------------------------------------------------------------------------
// Kernel 2: per row -- ballot-popcount bisection for a pivot P with
// #{S' > P+d} <= 31 and #{S' >= P-d} >= 32; band [P-d, P+d] rechecked with
// wave-cooperative exact fp32 dots; exact threshold among band; emit
// 512-bit adjacency mask + deg^-0.5. One wave per row, 4 rows/block.
// ---------------------------------------------------------------------------
__global__ __launch_bounds__(256) void thresh_mask(const float* __restrict__ S,
                                                   const float* __restrict__ x,
                                                   unsigned long long* __restrict__ masks,
                                                   float* __restrict__ dinv) {
    const int row  = blockIdx.x * 4 + (threadIdx.x >> 6);
    const int lane = threadIdx.x & 63;
    const float* Srow = S + (size_t)row * N;

    float v0[8];
#pragma unroll
    for (int k = 0; k < 8; k++) v0[k] = Srow[lane + 64 * k];   // col = lane + 64k

    // --- bisection: invariant cnt(lo) >= 32, cnt(hi) <= 31, cnt(p)=#{v>p} ---
    float lo = -1400.f, hi = 1400.f;   // |S'| <= ~1300 (diag chi2 max) + margin
    for (int it = 0; it < BISECT_ITERS; it++) {
        const float mid = 0.5f * (lo + hi);
        int c = 0;
#pragma unroll
        for (int k = 0; k < 8; k++) c += __popcll(__ballot(v0[k] > mid));
        if (c >= K_NEIGH) lo = mid; else hi = mid;
    }
    const float P   = 0.5f * (lo + hi);
    const float hiB = P + DELTA, loB = P - DELTA;

    // certainly-in count (<= 31 by construction)
    int cA = 0;
#pragma unroll
    for (int k = 0; k < 8; k++) cA += __popcll(__ballot(v0[k] > hiB));
    const int m_need = K_NEIGH - cA;   // >= 1

    // band candidates: one per lane
    int cnt = 0, myj = -1;
#pragma unroll
    for (int kq = 0; kq < 8; kq++) {
        unsigned long long bm = __ballot(v0[kq] >= loB && v0[kq] <= hiB);
        while (bm) {
            int bl = __ffsll(bm) - 1;
            bm &= bm - 1;
            if (cnt == lane) myj = bl + 64 * kq;
            cnt++;
        }
    }
    const int nc = cnt < 64 ? cnt : 64;

    // wave-cooperative exact dots: lane holds xi[q*256 + lane*4 .. +3]
    const int bb_ = row >> 9, ii = row & (N - 1);
    const float* xi = x + ((size_t)bb_ * N + ii) * C;
    float4 ai[4];
#pragma unroll
    for (int q = 0; q < 4; q++) ai[q] = *(const float4*)(xi + q * 256 + lane * 4);

    float ex = -INFINITY;
    for (int c2 = 0; c2 < nc; c2++) {
        const int j = __shfl(myj, c2);
        const float* xj = x + ((size_t)bb_ * N + j) * C;
        float s = 0.f;
#pragma unroll
        for (int q = 0; q < 4; q++) {
            float4 bv = *(const float4*)(xj + q * 256 + lane * 4);
            s = fmaf(ai[q].x, bv.x, s);
            s = fmaf(ai[q].y, bv.y, s);
            s = fmaf(ai[q].z, bv.z, s);
            s = fmaf(ai[q].w, bv.w, s);
        }
#pragma unroll
        for (int off = 32; off > 0; off >>= 1) s += __shfl_xor(s, off);
        if (lane == c2) ex = s;   // deterministic per (i,j)
    }

    // exact threshold T = m_need-th largest band value (tie-correct)
    float val = ex, T = -INFINITY;
    for (int it = 0; it < m_need; it++) {
        float M = val;
#pragma unroll
        for (int off = 32; off > 0; off >>= 1) M = fmaxf(M, __shfl_xor(M, off));
        T = M;
        unsigned long long ball = __ballot(val == M);
        int first = __ffsll(ball) - 1;
        if (lane == first) val = -INFINITY;
    }
    const int dec = (lane < nc && ex >= T) ? 1 : 0;

    // adjacency bits: certain-above -> 1, band -> exact decision, else 0
    int bits[8];
#pragma unroll
    for (int kq = 0; kq < 8; kq++) bits[kq] = (v0[kq] > hiB) ? 1 : 0;
    for (int c2 = 0; c2 < nc; c2++) {
        int j = __shfl(myj, c2);
        int d = __shfl(dec, c2);
        if ((j & 63) == lane) bits[j >> 6] = d;
    }

    unsigned long long msk[8];
    int deg = 0;
#pragma unroll
    for (int kq = 0; kq < 8; kq++) {
        msk[kq] = __ballot(bits[kq] != 0);
        deg += __popcll(msk[kq]);
    }
    if (lane == 0) {
#pragma unroll
        for (int kq = 0; kq < 8; kq++) masks[(size_t)row * 8 + kq] = msk[kq];
        dinv[row] = rsqrtf((float)deg);
    }
}

// ---------------------------------------------------------------------------
// Kernel 3: out[b,i,j] = maskbit ? dinv[b,i]*dinv[b,j] : 0  (writes over S')
// ---------------------------------------------------------------------------
__global__ __launch_bounds__(256) void scale_adj(float* __restrict__ Sout,
                                                 const unsigned long long* __restrict__ masks,
                                                 const float* __restrict__ dinv) {
    const int idx = blockIdx.x * 256 + threadIdx.x;   // float4 index
    const int jq = idx & 127;
    const int i  = (idx >> 7) & (N - 1);
    const int b  = idx >> 16;
    const int row = (b << 9) | i;
    const int j0 = jq * 4;

    const unsigned long long mk = masks[(size_t)row * 8 + (j0 >> 6)];
    const float di = dinv[row];
    float4 dj = ((const float4*)dinv)[(b << 7) | jq];

    float4 o;
    o.x = ((mk >> ((j0 + 0) & 63)) & 1ull) ? di * dj.x : 0.f;
    o.y = ((mk >> ((j0 + 1) & 63)) & 1ull) ? di * dj.y : 0.f;
    o.z = ((mk >> ((j0 + 2) & 63)) & 1ull) ? di * dj.z : 0.f;
    o.w = ((mk >> ((j0 + 3) & 63)) & 1ull) ? di * dj.w : 0.f;
    ((float4*)Sout)[idx] = o;
}

// ---------------------------------------------------------------------------
extern "C" void kernel_launch(void* const* d_in, const int* in_sizes, int n_in,
                              void* d_out, int out_size, void* d_ws, size_t ws_size,
                              hipStream_t stream) {
    const float* x = (const float*)d_in[0];
    float* out = (float*)d_out;                      // stages S', then final out
    unsigned long long* masks = (unsigned long long*)d_ws;     // B*N*8 u64 = 2MB
    float* dinv = (float*)(masks + (size_t)B * N * 8);         // B*N floats

    gemm_f16<<<dim3(B * 4), 512, 0, stream>>>(x, out);         // 256 blocks = 1/CU
    thresh_mask<<<B * N / 4, 256, 0, stream>>>(out, x, masks, dinv);
    const int total4 = B * N * N / 4;
    scale_adj<<<total4 / 256, 256, 0, stream>>>(out, masks, dinv);
}

// Round 3
// 272.520 us; speedup vs baseline: 1.3520x; 1.1307x over previous
//
#include <hip/hip_runtime.h>
#include <hip/hip_bf16.h>
#include <math.h>

#define B 64
#define N 512
#define C 1024
#define K_NEIGH 32
// Band half-width: need DELTA - bisect_window/2 - E' > E', where
// E' = E_gemm + E_store. E_gemm ~ 0.15 (9-sigma fp16-hi GEMM error);
// E_store <= 0.07 (fp16 storage rounding for band-relevant |v| <= 256).
// window = 2800/2^12 = 0.68 -> DELTA > 0.34 + 0.44 = 0.78; DELTA = 0.9.
// Non-band elements are strictly separated from the true rank-32 cut;
// band candidates are exactly rechecked in fp32 (bitwise-matching dots).
#define DELTA 0.9f
#define BISECT_ITERS 12

typedef __attribute__((ext_vector_type(8))) _Float16 half8;
typedef __attribute__((ext_vector_type(4))) float f32x4;

__device__ __forceinline__ half8 cvt8(float4 a, float4 b) {
    half8 g;
    g[0] = (_Float16)a.x; g[1] = (_Float16)a.y; g[2] = (_Float16)a.z; g[3] = (_Float16)a.w;
    g[4] = (_Float16)b.x; g[5] = (_Float16)b.y; g[6] = (_Float16)b.z; g[7] = (_Float16)b.w;
    return g;
}

// ---------------------------------------------------------------------------
// Kernel 1: S16[b] = fp16( fp16(x[b]) * fp16(x[b])^T ) via f16 MFMA.
// 256x256 tile, 512 thr = 8 waves (2x4 of 128x64), BK=32, 2-phase pipeline:
//   issue global loads for K-step t+1 (regs) -> ds_read+MFMA on buf[cur]
//   -> cvt+ds_write into buf[cur^1] -> ONE barrier -> flip.
// S' is stored as fp16 (33.5 MB): keeps the x + S' + out working set under
// the 256 MB L3, halves gemm write + thresh read traffic.
// ---------------------------------------------------------------------------
__global__ __launch_bounds__(512, 2) void gemm_f16(const float* __restrict__ x,
                                                   _Float16* __restrict__ S16) {
    __shared__ half8 Ah[2][1024];   // 2 x 16KB  (4 granule-cols x 256 rows)
    __shared__ half8 Bh[2][1024];   // 2 x 16KB

    // XCD-aware swizzle: XCD = id%8 owns batches xcd*8..+7 (4 tiles each
    // consecutive) -> tiles of one batch co-resident, share x[b] in L2.
    const int id   = blockIdx.x;           // 0..255
    const int xcd  = id & 7;
    const int slot = id >> 3;              // 0..31
    const int b    = xcd * 8 + (slot >> 2);
    const int tile = slot & 3;
    const int ti = tile >> 1, tj = tile & 1;
    const int row0 = ti * 256;
    const int col0 = tj * 256;
    const float* xb = x + (size_t)b * N * C;
    const bool diag = (ti == tj);

    const int t    = threadIdx.x;
    const int w    = t >> 6;
    const int lane = t & 63;
    const int quad = lane >> 4;
    const int lid  = lane & 15;
    const int wr   = (w >> 2) * 128;       // 2 wave-rows of 128
    const int wc   = (w & 3) * 64;         // 4 wave-cols of 64

    // staging: thread t -> row (t>>1), k-half (t&1)*16 floats (granules s0,s0+1)
    const int srow = t >> 1;
    const int s0   = (t & 1) * 2;
    const int koff = (t & 1) * 16;

    f32x4 acc[8][4];
#pragma unroll
    for (int r = 0; r < 8; r++)
#pragma unroll
        for (int c = 0; c < 4; c++)
#pragma unroll
            for (int e = 0; e < 4; e++) acc[r][c][e] = 0.f;

    const float* pArow = xb + (size_t)(row0 + srow) * C + koff;
    const float* pBrow = xb + (size_t)(col0 + srow) * C + koff;

    float4 ra[4], rb[4];
    // ---- prologue: stage K-step 0 ----
    {
        const float4* pa = (const float4*)pArow;
#pragma unroll
        for (int i = 0; i < 4; i++) ra[i] = pa[i];
        if (!diag) {
            const float4* pb = (const float4*)pBrow;
#pragma unroll
            for (int i = 0; i < 4; i++) rb[i] = pb[i];
        }
        Ah[0][s0 * 256 + srow]       = cvt8(ra[0], ra[1]);
        Ah[0][(s0 + 1) * 256 + srow] = cvt8(ra[2], ra[3]);
        if (!diag) {
            Bh[0][s0 * 256 + srow]       = cvt8(rb[0], rb[1]);
            Bh[0][(s0 + 1) * 256 + srow] = cvt8(rb[2], rb[3]);
        }
    }
    __syncthreads();

    int cur = 0;
    const int NIT = C / 32;                 // 32 K-steps
    for (int it = 0; it < NIT; ++it) {
        const bool more = (it + 1) < NIT;
        // ---- issue next-tile loads early (latency hides under MFMA) ----
        if (more) {
            const float4* pa = (const float4*)(pArow + (it + 1) * 32);
#pragma unroll
            for (int i = 0; i < 4; i++) ra[i] = pa[i];
            if (!diag) {
                const float4* pb = (const float4*)(pBrow + (it + 1) * 32);
#pragma unroll
                for (int i = 0; i < 4; i++) rb[i] = pb[i];
            }
        }
        // ---- compute current buffer ----
        const half8* Ab = &Ah[cur][0];
        const half8* Bb = diag ? Ab : &Bh[cur][0];
        half8 vb[4];
#pragma unroll
        for (int c = 0; c < 4; c++) vb[c] = Bb[quad * 256 + wc + c * 16 + lid];
        __builtin_amdgcn_s_setprio(1);
#pragma unroll
        for (int r = 0; r < 8; r++) {
            half8 va = Ab[quad * 256 + wr + r * 16 + lid];
#pragma unroll
            for (int c = 0; c < 4; c++)
                acc[r][c] = __builtin_amdgcn_mfma_f32_16x16x32_f16(va, vb[c], acc[r][c], 0, 0, 0);
        }
        __builtin_amdgcn_s_setprio(0);
        // ---- convert + write next tile into the other buffer ----
        if (more) {
            const int nb = cur ^ 1;
            Ah[nb][s0 * 256 + srow]       = cvt8(ra[0], ra[1]);
            Ah[nb][(s0 + 1) * 256 + srow] = cvt8(ra[2], ra[3]);
            if (!diag) {
                Bh[nb][s0 * 256 + srow]       = cvt8(rb[0], rb[1]);
                Bh[nb][(s0 + 1) * 256 + srow] = cvt8(rb[2], rb[3]);
            }
        }
        __syncthreads();
        cur ^= 1;
    }

    _Float16* Sb = S16 + (size_t)b * N * N;
#pragma unroll
    for (int r = 0; r < 8; r++) {
#pragma unroll
        for (int c = 0; c < 4; c++) {
#pragma unroll
            for (int e = 0; e < 4; e++) {
                const int grow = row0 + wr + r * 16 + quad * 4 + e;
                const int gcol = col0 + wc + c * 16 + lid;
                Sb[(size_t)grow * N + gcol] = (_Float16)acc[r][c][e];
            }
        }
    }
}

// ---------------------------------------------------------------------------
// Kernel 2: per row -- ballot-popcount bisection for a pivot P with
// #{S' > P+d} <= 31 and #{S' >= P-d} >= 32; band [P-d, P+d] rechecked with
// wave-cooperative exact fp32 dots; exact threshold among band; emit
// 512-bit adjacency mask + deg^-0.5. One wave per row, 4 rows/block.
// S' is fp16; decisions on fp16 values are conservative per the DELTA budget.
// ---------------------------------------------------------------------------
__global__ __launch_bounds__(256) void thresh_mask(const _Float16* __restrict__ S16,
                                                   const float* __restrict__ x,
                                                   unsigned long long* __restrict__ masks,
                                                   float* __restrict__ dinv) {
    // XCD-aware swizzle: XCD = id%8 owns batches xcd*8..+7, so each XCD's
    // band dots re-read its own 2MB x[b] slice from its private L2.
    const int id   = blockIdx.x;               // 0..8191
    const int xcd  = id & 7;
    const int slot = id >> 3;                  // 0..1023
    const int bsw  = xcd * 8 + (slot >> 7);    // batch
    const int rblk = slot & 127;               // 4-row block within batch
    const int row  = bsw * N + rblk * 4 + (threadIdx.x >> 6);
    const int lane = threadIdx.x & 63;
    const _Float16* Srow = S16 + (size_t)row * N;

    float v0[8];
#pragma unroll
    for (int k = 0; k < 8; k++) v0[k] = (float)Srow[lane + 64 * k];   // col = lane + 64k

    // --- bisection: invariant cnt(lo) >= 32, cnt(hi) <= 31, cnt(p)=#{v>p} ---
    float lo = -1400.f, hi = 1400.f;   // |S'| <= ~1300 (diag chi2 max) + margin
    for (int it = 0; it < BISECT_ITERS; it++) {
        const float mid = 0.5f * (lo + hi);
        int c = 0;
#pragma unroll
        for (int k = 0; k < 8; k++) c += __popcll(__ballot(v0[k] > mid));
        if (c >= K_NEIGH) lo = mid; else hi = mid;
    }
    const float P   = 0.5f * (lo + hi);
    const float hiB = P + DELTA, loB = P - DELTA;

    // certainly-in count (<= 31 by construction: hiB > hi)
    int cA = 0;
#pragma unroll
    for (int k = 0; k < 8; k++) cA += __popcll(__ballot(v0[k] > hiB));
    const int m_need = K_NEIGH - cA;   // >= 1 (loB < lo)

    // band candidates: one per lane
    int cnt = 0, myj = -1;
#pragma unroll
    for (int kq = 0; kq < 8; kq++) {
        unsigned long long bm = __ballot(v0[kq] >= loB && v0[kq] <= hiB);
        while (bm) {
            int bl = __ffsll(bm) - 1;
            bm &= bm - 1;
            if (cnt == lane) myj = bl + 64 * kq;
            cnt++;
        }
    }
    const int nc = cnt < 64 ? cnt : 64;

    // wave-cooperative exact dots: lane holds xi[q*256 + lane*4 .. +3]
    const int bb_ = row >> 9, ii = row & (N - 1);
    const float* xi = x + ((size_t)bb_ * N + ii) * C;
    float4 ai[4];
#pragma unroll
    for (int q = 0; q < 4; q++) ai[q] = *(const float4*)(xi + q * 256 + lane * 4);

    float ex = -INFINITY;
    for (int c2 = 0; c2 < nc; c2++) {
        const int j = __shfl(myj, c2);
        const float* xj = x + ((size_t)bb_ * N + j) * C;
        float s = 0.f;
#pragma unroll
        for (int q = 0; q < 4; q++) {
            float4 bv = *(const float4*)(xj + q * 256 + lane * 4);
            s = fmaf(ai[q].x, bv.x, s);
            s = fmaf(ai[q].y, bv.y, s);
            s = fmaf(ai[q].z, bv.z, s);
            s = fmaf(ai[q].w, bv.w, s);
        }
#pragma unroll
        for (int off = 32; off > 0; off >>= 1) s += __shfl_xor(s, off);
        if (lane == c2) ex = s;   // deterministic per (i,j)
    }

    // exact threshold T = m_need-th largest band value (tie-correct)
    float val = ex, T = -INFINITY;
    for (int it = 0; it < m_need; it++) {
        float M = val;
#pragma unroll
        for (int off = 32; off > 0; off >>= 1) M = fmaxf(M, __shfl_xor(M, off));
        T = M;
        unsigned long long ball = __ballot(val == M);
        int first = __ffsll(ball) - 1;
        if (lane == first) val = -INFINITY;
    }
    const int dec = (lane < nc && ex >= T) ? 1 : 0;

    // adjacency bits: certain-above -> 1, band -> exact decision, else 0
    int bits[8];
#pragma unroll
    for (int kq = 0; kq < 8; kq++) bits[kq] = (v0[kq] > hiB) ? 1 : 0;
    for (int c2 = 0; c2 < nc; c2++) {
        int j = __shfl(myj, c2);
        int d = __shfl(dec, c2);
        if ((j & 63) == lane) bits[j >> 6] = d;
    }

    unsigned long long msk[8];
    int deg = 0;
#pragma unroll
    for (int kq = 0; kq < 8; kq++) {
        msk[kq] = __ballot(bits[kq] != 0);
        deg += __popcll(msk[kq]);
    }
    if (lane == 0) {
#pragma unroll
        for (int kq = 0; kq < 8; kq++) masks[(size_t)row * 8 + kq] = msk[kq];
        dinv[row] = rsqrtf((float)deg);
    }
}

// ---------------------------------------------------------------------------
// Kernel 3: out[b,i,j] = maskbit ? dinv[b,i]*dinv[b,j] : 0
// ---------------------------------------------------------------------------
__global__ __launch_bounds__(256) void scale_adj(float* __restrict__ Sout,
                                                 const unsigned long long* __restrict__ masks,
                                                 const float* __restrict__ dinv) {
    const int idx = blockIdx.x * 256 + threadIdx.x;   // float4 index
    const int jq = idx & 127;
    const int i  = (idx >> 7) & (N - 1);
    const int b  = idx >> 16;
    const int row = (b << 9) | i;
    const int j0 = jq * 4;

    const unsigned long long mk = masks[(size_t)row * 8 + (j0 >> 6)];
    const float di = dinv[row];
    float4 dj = ((const float4*)dinv)[(b << 7) | jq];

    float4 o;
    o.x = ((mk >> ((j0 + 0) & 63)) & 1ull) ? di * dj.x : 0.f;
    o.y = ((mk >> ((j0 + 1) & 63)) & 1ull) ? di * dj.y : 0.f;
    o.z = ((mk >> ((j0 + 2) & 63)) & 1ull) ? di * dj.z : 0.f;
    o.w = ((mk >> ((j0 + 3) & 63)) & 1ull) ? di * dj.w : 0.f;
    ((float4*)Sout)[idx] = o;
}

// ---------------------------------------------------------------------------
extern "C" void kernel_launch(void* const* d_in, const int* in_sizes, int n_in,
                              void* d_out, int out_size, void* d_ws, size_t ws_size,
                              hipStream_t stream) {
    const float* x = (const float*)d_in[0];
    float* out = (float*)d_out;                      // final fp32 output
    _Float16* S16 = (_Float16*)d_out;                // staged fp16 S' (first 33.5MB)
    unsigned long long* masks = (unsigned long long*)d_ws;     // B*N*8 u64 = 2MB
    float* dinv = (float*)(masks + (size_t)B * N * 8);         // B*N floats

    gemm_f16<<<dim3(B * 4), 512, 0, stream>>>(x, S16);         // 256 blocks = 1/CU
    thresh_mask<<<B * N / 4, 256, 0, stream>>>(S16, x, masks, dinv);
    const int total4 = B * N * N / 4;
    scale_adj<<<total4 / 256, 256, 0, stream>>>(out, masks, dinv);
}